// Round 10
// baseline (1851.234 us; speedup 1.0000x reference)
//
#include <hip/hip_runtime.h>
#include <hip/hip_bf16.h>

#define B_ 2048
#define T_ 128
#define F_ 64
#define U_ 512
#define FOURU 2048
#define OUTS 32
#define ROWS 128      // batch rows per group
#define COLSB 128     // z cols per block (4 gates x 32 units)
#define KTOT 576      // 64 (x) + 512 (h)
#define LDSTR 584     // padded LDS col stride (elements)

typedef __attribute__((ext_vector_type(8))) short bf16x8;
typedef __attribute__((ext_vector_type(4))) float f32x4;

// workspace layout (bytes). First 69632+2MB zeroed every launch:
//   dw [0..16383]       flags: group gb, block gu at dw gb*1024+gu*64 (256B line-isolated)
//   dw [16384..16639]   regist counters (16 groups x 16dw)
//   dw [16640..16895]   xcd table (16 groups x 16dw)
#define OFF_CNT   0
#define OFF_HBUF  69632
#define OFF_WT    (OFF_HBUF + 2*B_*U_*2)
#define OFF_WDEC  (OFF_WT + FOURU*KTOT*2)
#define OFF_DWT   (OFF_WDEC + FOURU*U_*2)
#define OFF_BDEC  (OFF_DWT + F_*U_*2)
#define OFF_XBF   (OFF_BDEC + FOURU*4)
#define WS_TOTAL  (OFF_XBF + (size_t)T_*B_*F_*2)

__device__ __forceinline__ short f2bf(float f) {
  union { float f; unsigned u; } a; a.f = f;
  unsigned u = a.u;
  unsigned r = u + 0x7FFFu + ((u >> 16) & 1u);  // RNE
  return (short)(r >> 16);
}
__device__ __forceinline__ float sigm(float x){ return 1.0f/(1.0f+__expf(-x)); }
__device__ __forceinline__ float tanh_(float x){ return 1.0f - 2.0f/(1.0f+__expf(2.0f*x)); }

// ---------------- prep kernels ----------------
__global__ void prep_wt(const float* __restrict__ Wx, const float* __restrict__ Wh,
                        short* __restrict__ Wt) {
  int idx = blockIdx.x*256 + threadIdx.x;
  if (idx >= FOURU*KTOT) return;
  int c = idx / KTOT, k = idx % KTOT;
  float v = (k < F_) ? Wx[(size_t)k*FOURU + c] : Wh[(size_t)(k-F_)*FOURU + c];
  Wt[idx] = f2bf(v);
}
__global__ void prep_wdec(const float* __restrict__ Wh, const float* __restrict__ Wx,
                          const float* __restrict__ Dw, short* __restrict__ Wdec) {
  int idx = blockIdx.x*256 + threadIdx.x;
  if (idx >= FOURU*U_) return;
  int c = idx / U_, u = idx % U_;
  float a = Wh[(size_t)u*FOURU + c];
  for (int f=0; f<F_; ++f) a += Dw[u*F_ + f] * Wx[(size_t)f*FOURU + c];
  Wdec[idx] = f2bf(a);
}
__global__ void prep_bdec(const float* __restrict__ bv, const float* __restrict__ db,
                          const float* __restrict__ Wx, float* __restrict__ bdec) {
  int c = blockIdx.x*256 + threadIdx.x;
  if (c >= FOURU) return;
  float a = bv[c];
  for (int f=0; f<F_; ++f) a += db[f]*Wx[(size_t)f*FOURU + c];
  bdec[c] = a;
}
__global__ void prep_dwt(const float* __restrict__ Dw, short* __restrict__ Dwt) {
  int idx = blockIdx.x*256 + threadIdx.x;
  if (idx >= F_*U_) return;
  int f = idx / U_, u = idx % U_;
  Dwt[idx] = f2bf(Dw[u*F_ + f]);
}
__global__ void prep_x(const float* __restrict__ in, short* __restrict__ xbf) {
  int idx = blockIdx.x*256 + threadIdx.x;
  if (idx >= T_*B_*F_) return;
  int f = idx % F_, b = (idx / F_) % B_, t = idx / (F_*B_);
  xbf[idx] = f2bf(in[((size_t)b*T_ + t)*F_ + f]);
}

// ---------------- main persistent kernel ----------------
// 1024 threads = 16 waves; 1 block/CU (LDS-bound) -> 4 waves/SIMD.
// R9 compute structure unchanged. Sync de-contended: 1 poller lane per flag
// per block (was 4), flags 256B apart (1 L2 line each), s_sleep(2) backoff --
// the release store no longer queues behind a storm of polls at the L2
// coherent point.
__global__ __launch_bounds__(1024, 4) void lstm_main(
    const short* __restrict__ xbf, const short* __restrict__ Wt,
    const short* __restrict__ Wdec, const short* __restrict__ Dwt,
    const float* __restrict__ bvec, const float* __restrict__ bdec,
    const float* __restrict__ dbv, short* hbuf, unsigned* cnt,
    float* __restrict__ out)
{
  __shared__ short wlds[COLSB*LDSTR];   // 149,504 B
  __shared__ int sSame;
  const int tid = threadIdx.x;
  const int bidx = blockIdx.x;
  // a group's 16 blocks share bidx%8 -> same XCD under round-robin dispatch
  // (perf heuristic; verified at runtime below, fallback is cross-XCD safe)
  const int gb = (bidx & 7)*2 + (bidx >> 7);   // batch group 0..15
  const int gu = (bidx >> 3) & 15;             // unit group 0..15

  unsigned* flags  = cnt + gb*1024;            // 16 flags, 256B spaced
  unsigned* myFlag = flags + gu*64;
  unsigned* regCnt = cnt + 16384 + gb*16;
  unsigned* xcdTab = cnt + 16640 + gb*16;

  // ---- runtime XCD-uniformity check for this group ----
  {
    unsigned xcc;
    asm volatile("s_getreg_b32 %0, hwreg(HW_REG_XCC_ID)" : "=s"(xcc));
    if (tid == 0) {
      __hip_atomic_store(&xcdTab[gu], xcc + 1u, __ATOMIC_RELAXED, __HIP_MEMORY_SCOPE_AGENT);
      __hip_atomic_fetch_add(regCnt, 1u, __ATOMIC_RELEASE, __HIP_MEMORY_SCOPE_AGENT);
      while (__hip_atomic_fetch_add(regCnt, 0u, __ATOMIC_RELAXED, __HIP_MEMORY_SCOPE_AGENT) < 16u)
        __builtin_amdgcn_s_sleep(2);
      __builtin_amdgcn_fence(__ATOMIC_ACQUIRE, "agent");
      unsigned x0 = __hip_atomic_load(&xcdTab[0], __ATOMIC_RELAXED, __HIP_MEMORY_SCOPE_AGENT);
      int same = 1;
      for (int i = 1; i < 16; ++i)
        same &= (__hip_atomic_load(&xcdTab[i], __ATOMIC_RELAXED, __HIP_MEMORY_SCOPE_AGENT) == x0);
      sSame = same;
    }
  }

  // ---- load warm-up weight slice to LDS (col=tid>>3, 72 B each) ----
  {
    const int c = tid >> 3, q = tid & 7;
    const int gate = (c >> 4) & 3;
    const int u = gu*32 + ((c >> 6) << 4) + (c & 15);
    const int gcol = gate*512 + u;
    const short* src = Wt + (size_t)gcol*KTOT + q*72;
    short* dst = wlds + c*LDSTR + q*72;
    #pragma unroll
    for (int j=0;j<9;j++)
      *(bf16x8*)(dst + j*8) = *(const bf16x8*)(src + j*8);
  }
  __syncthreads();
  const bool fastSync = (sSame != 0);

  const int w = tid >> 6, lane = tid & 63;
  const int wm = w >> 1, wn = w & 1;           // 8 row-groups x 2 col-halves
  const int l15 = lane & 15, kh = lane >> 4;

  const int ucol = gu*32 + wn*16 + l15;        // unit column this lane updates
  float bia[4], biaD[4];
  #pragma unroll
  for (int g=0; g<4; ++g){ bia[g] = bvec[g*512 + ucol]; biaD[g] = bdec[g*512 + ucol]; }

  float cst[4] = {};                           // c state (fp32, persistent)
  const int rowA = gb*ROWS + wm*16 + l15;      // A-frag row for this lane

  // ---- register B-cache: ks 0..1 of the h-region (32 regs, fits budget) ----
  bf16x8 Bc[2][4];
  auto loadBc = [&]() {
    #pragma unroll
    for (int ks=0; ks<2; ++ks)
      #pragma unroll
      for (int g=0; g<4; ++g)
        Bc[ks][g] = *(const bf16x8*)(wlds + (size_t)(wn*64 + 16*g + l15)*LDSTR + 64 + ks*32 + kh*8);
  };
  loadBc();

  f32x4 acc[4];
  // x-part helper (K 0..63): assigns acc fresh
  auto do_x = [&](int tt) {
    const short* xp = xbf + ((size_t)tt*B_ + rowA)*F_ + kh*8;
    bf16x8 a0 = *(const bf16x8*)(xp);
    bf16x8 a1 = *(const bf16x8*)(xp + 32);
    #pragma unroll
    for (int g=0; g<4; ++g) {
      bf16x8 b0 = *(const bf16x8*)(wlds + (size_t)(wn*64 + 16*g + l15)*LDSTR + kh*8);
      bf16x8 b1 = *(const bf16x8*)(wlds + (size_t)(wn*64 + 16*g + l15)*LDSTR + 32 + kh*8);
      f32x4 z = {0.f,0.f,0.f,0.f};
      z = __builtin_amdgcn_mfma_f32_16x16x32_bf16(a0, b0, z, 0,0,0);
      acc[g] = __builtin_amdgcn_mfma_f32_16x16x32_bf16(a1, b1, z, 0,0,0);
    }
  };
  do_x(0);   // h(0)=0 (buf0 zeroed), so step 0 = x-part + zero h-contribution

  for (int t = 0; t < 160; ++t) {
    // ---- wait: all 16 group flags >= t (1 poller lane per flag) ----
    if (t > 0) {
      if (fastSync) {
        if (tid < 64) {
          unsigned* fl = flags + (tid & 15)*64;
          const bool poller = (tid < 16);
          for (;;) {
            unsigned vv = poller
              ? __hip_atomic_load(fl, __ATOMIC_RELAXED, __HIP_MEMORY_SCOPE_AGENT)
              : (unsigned)t;
            if (__ballot(vv >= (unsigned)t) == ~0ull) break;
            __builtin_amdgcn_s_sleep(2);
          }
          asm volatile("buffer_inv sc0" ::: "memory");     // L1 invalidate
          asm volatile("s_waitcnt vmcnt(0)" ::: "memory");
        }
      } else {
        if (tid < 64) {
          unsigned* fl = flags + (tid & 15)*64;
          const bool poller = (tid < 16);
          for (;;) {
            unsigned vv = poller
              ? __hip_atomic_fetch_add(fl, 0u, __ATOMIC_RELAXED, __HIP_MEMORY_SCOPE_AGENT)
              : (unsigned)t;
            if (__ballot(vv >= (unsigned)t) == ~0ull) break;
            __builtin_amdgcn_s_sleep(2);
          }
        }
        if (tid == 0)
          __builtin_amdgcn_fence(__ATOMIC_ACQUIRE, "agent");
      }
      __syncthreads();
    }

    const short* hcur = hbuf + (size_t)(t & 1)*B_*U_;
    short* hnxt = hbuf + (size_t)((t+1) & 1)*B_*U_;

    // ---- pred s = t-128 (reads h(t) just finalized; distributed gu<8, w<4) ----
    if (t >= 128 && gu < 8 && w < 4) {
      const int s = t - 128;
      const int pr0 = gb*ROWS + gu*16 + l15;
      f32x4 pa = {0.f,0.f,0.f,0.f};
      #pragma unroll
      for (int ks=0; ks<16; ++ks) {
        bf16x8 a = *(const bf16x8*)(hcur + (size_t)pr0*U_ + ks*32 + kh*8);
        bf16x8 b = *(const bf16x8*)(Dwt + (size_t)(w*16 + l15)*U_ + ks*32 + kh*8);
        pa = __builtin_amdgcn_mfma_f32_16x16x32_bf16(a, b, pa, 0,0,0);
      }
      const int col = w*16 + l15;
      const float dbc = dbv[col];
      #pragma unroll
      for (int r=0; r<4; ++r) {
        const int orow = gb*ROWS + gu*16 + kh*4 + r;
        out[((size_t)orow*OUTS + s)*F_ + col] = pa[r] + dbc;
      }
    }
    if (t == 159) break;
    if (t == 128) {   // swap k-region 64..575 to folded decode weights
      __syncthreads();
      const int c = tid >> 3, q = tid & 7;
      const int gate = (c >> 4) & 3;
      const int u = gu*32 + ((c >> 6) << 4) + (c & 15);
      const int gcol = gate*512 + u;
      const short* src = Wdec + (size_t)gcol*U_ + q*64;
      short* dst = wlds + c*LDSTR + 64 + q*64;
      #pragma unroll
      for (int j=0;j<8;j++)
        *(bf16x8*)(dst + j*8) = *(const bf16x8*)(src + j*8);
      __syncthreads();
      loadBc();       // refresh register B-cache from the new weights
    }

    // ---- h-part: K 64..575, 16 chunks; ks 0..1 hit the register cache ----
    {
      const short* hp = hcur + (size_t)rowA*U_ + kh*8;
      #pragma unroll
      for (int ks=0; ks<16; ++ks) {
        bf16x8 a = *(const bf16x8*)(hp + ks*32);
        #pragma unroll
        for (int g=0; g<4; ++g) {
          bf16x8 b = (ks < 2) ? Bc[ks][g]
            : *(const bf16x8*)(wlds + (size_t)(wn*64 + 16*g + l15)*LDSTR + 64 + ks*32 + kh*8);
          acc[g] = __builtin_amdgcn_mfma_f32_16x16x32_bf16(a, b, acc[g], 0,0,0);
        }
      }
    }

    // ---- gates + state update + h2 store (C/D: col=l15, row=kh*4+r) ----
    {
      const bool warm = (t < T_);
      #pragma unroll
      for (int r=0; r<4; ++r) {
        float zi = acc[0][r] + (warm ? bia[0] : biaD[0]);
        float zf = acc[1][r] + (warm ? bia[1] : biaD[1]);
        float zg = acc[2][r] + (warm ? bia[2] : biaD[2]);
        float zo = acc[3][r] + (warm ? bia[3] : biaD[3]);
        float ig = sigm(zi), fg = sigm(zf), gg = tanh_(zg), og = sigm(zo);
        float c2 = fmaf(fg, cst[r], ig*gg);
        cst[r] = c2;
        float h2 = og*tanh_(c2);
        const int row = gb*ROWS + wm*16 + kh*4 + r;
        hnxt[(size_t)row*U_ + ucol] = f2bf(h2);
      }
    }

    // ---- release: drain stores (syncthreads emits vmcnt(0)), set flag ----
    __syncthreads();
    if (tid == 0) {
      if (fastSync)
        __hip_atomic_store(myFlag, (unsigned)(t+1), __ATOMIC_RELAXED, __HIP_MEMORY_SCOPE_AGENT);
      else
        __hip_atomic_fetch_add(myFlag, 1u, __ATOMIC_RELEASE, __HIP_MEMORY_SCOPE_AGENT);
    }

    // ---- next step's x-part (shadows inter-block flag latency) ----
    #pragma unroll
    for (int g=0; g<4; ++g) acc[g] = (f32x4){0.f,0.f,0.f,0.f};
    if (t + 1 < T_) do_x(t+1);
  }
}

extern "C" void kernel_launch(void* const* d_in, const int* in_sizes, int n_in,
                              void* d_out, int out_size, void* d_ws, size_t ws_size,
                              hipStream_t stream) {
  const float* inputs = (const float*)d_in[0];
  const float* Wx = (const float*)d_in[1];
  const float* Wh = (const float*)d_in[2];
  const float* bv = (const float*)d_in[3];
  const float* Dw = (const float*)d_in[4];
  const float* db = (const float*)d_in[5];
  float* out = (float*)d_out;
  char* ws = (char*)d_ws;
  if (ws_size < WS_TOTAL) return;   // fail loudly (output stays poisoned)

  unsigned* cnt = (unsigned*)(ws + OFF_CNT);
  short* hbuf = (short*)(ws + OFF_HBUF);
  short* Wt   = (short*)(ws + OFF_WT);
  short* Wdec = (short*)(ws + OFF_WDEC);
  short* Dwt  = (short*)(ws + OFF_DWT);
  float* bdec = (float*)(ws + OFF_BDEC);
  short* xbf  = (short*)(ws + OFF_XBF);

  // zero sync area + h buffer 0 (every launch -> deterministic)
  hipMemsetAsync(d_ws, 0, OFF_HBUF + (size_t)B_*U_*2, stream);
  prep_wt  <<<(FOURU*KTOT+255)/256, 256, 0, stream>>>(Wx, Wh, Wt);
  prep_wdec<<<(FOURU*U_ +255)/256, 256, 0, stream>>>(Wh, Wx, Dw, Wdec);
  prep_bdec<<<(FOURU     +255)/256, 256, 0, stream>>>(bv, db, Wx, bdec);
  prep_dwt <<<(F_*U_     +255)/256, 256, 0, stream>>>(Dw, Dwt);
  prep_x   <<<(T_*B_*F_  +255)/256, 256, 0, stream>>>(inputs, xbf);
  lstm_main<<<256, 1024, 0, stream>>>(xbf, Wt, Wdec, Dwt, bv, bdec, db, hbuf, cnt, out);
}

// Round 11
// 1832.390 us; speedup vs baseline: 1.0103x; 1.0103x over previous
//
#include <hip/hip_runtime.h>
#include <hip/hip_bf16.h>

#define B_ 2048
#define T_ 128
#define F_ 64
#define U_ 512
#define FOURU 2048
#define OUTS 32
#define ROWS 128      // batch rows per group
#define COLSB 128     // z cols per block (4 gates x 32 units)
#define KTOT 576      // 64 (x) + 512 (h)
#define LDSTR 584     // padded LDS col stride (elements)

typedef __attribute__((ext_vector_type(8))) short bf16x8;
typedef __attribute__((ext_vector_type(4))) float f32x4;

// workspace layout (bytes). First 69632 B zeroed every launch:
//   dw [0..16383]       flags: group gb, block gu at dw gb*1024+gu*64 (256B line-isolated)
//   dw [16384..16639]   regist counters (16 groups x 16dw)
//   dw [16640..16895]   xcd table (16 groups x 16dw)
#define OFF_CNT   0
#define OFF_HBUF  69632
#define OFF_WT    (OFF_HBUF + 2*B_*U_*2)
#define OFF_WDEC  (OFF_WT + FOURU*KTOT*2)
#define OFF_DWT   (OFF_WDEC + FOURU*U_*2)
#define OFF_BDEC  (OFF_DWT + F_*U_*2)
#define OFF_XBF   (OFF_BDEC + FOURU*4)
#define WS_TOTAL  (OFF_XBF + (size_t)T_*B_*F_*2)

__device__ __forceinline__ short f2bf(float f) {
  union { float f; unsigned u; } a; a.f = f;
  unsigned u = a.u;
  unsigned r = u + 0x7FFFu + ((u >> 16) & 1u);  // RNE
  return (short)(r >> 16);
}
__device__ __forceinline__ float sigm(float x){ return 1.0f/(1.0f+__expf(-x)); }
__device__ __forceinline__ float tanh_(float x){ return 1.0f - 2.0f/(1.0f+__expf(2.0f*x)); }

// ---------------- prep kernels ----------------
__global__ void prep_wt(const float* __restrict__ Wx, const float* __restrict__ Wh,
                        short* __restrict__ Wt) {
  int idx = blockIdx.x*256 + threadIdx.x;
  if (idx >= FOURU*KTOT) return;
  int c = idx / KTOT, k = idx % KTOT;
  float v = (k < F_) ? Wx[(size_t)k*FOURU + c] : Wh[(size_t)(k-F_)*FOURU + c];
  Wt[idx] = f2bf(v);
}
__global__ void prep_wdec(const float* __restrict__ Wh, const float* __restrict__ Wx,
                          const float* __restrict__ Dw, short* __restrict__ Wdec) {
  int idx = blockIdx.x*256 + threadIdx.x;
  if (idx >= FOURU*U_) return;
  int c = idx / U_, u = idx % U_;
  float a = Wh[(size_t)u*FOURU + c];
  for (int f=0; f<F_; ++f) a += Dw[u*F_ + f] * Wx[(size_t)f*FOURU + c];
  Wdec[idx] = f2bf(a);
}
__global__ void prep_bdec(const float* __restrict__ bv, const float* __restrict__ db,
                          const float* __restrict__ Wx, float* __restrict__ bdec) {
  int c = blockIdx.x*256 + threadIdx.x;
  if (c >= FOURU) return;
  float a = bv[c];
  for (int f=0; f<F_; ++f) a += db[f]*Wx[(size_t)f*FOURU + c];
  bdec[c] = a;
}
__global__ void prep_dwt(const float* __restrict__ Dw, short* __restrict__ Dwt) {
  int idx = blockIdx.x*256 + threadIdx.x;
  if (idx >= F_*U_) return;
  int f = idx / U_, u = idx % U_;
  Dwt[idx] = f2bf(Dw[u*F_ + f]);
}
__global__ void prep_x(const float* __restrict__ in, short* __restrict__ xbf) {
  int idx = blockIdx.x*256 + threadIdx.x;
  if (idx >= T_*B_*F_) return;
  int f = idx % F_, b = (idx / F_) % B_, t = idx / (F_*B_);
  xbf[idx] = f2bf(in[((size_t)b*T_ + t)*F_ + f]);
}

// ---------------- main persistent kernel ----------------
// 1024 threads = 16 waves; 1 block/CU (LDS-bound) -> 4 waves/SIMD.
// R10 structure; h-GEMM explicitly software-pipelined: 8 A-loads hoisted per
// half (L2 latencies overlap), B-fragments double-buffered (ds_read of ks+1
// issued before MFMA of ks). Lockstep waves can't hide latency for each
// other, so per-wave ILP must do it. Bc cache dropped (R9: neutral) to pay
// the register bill (~112 < 128/wave cap; spill canary = WRITE_SIZE).
__global__ __launch_bounds__(1024, 4) void lstm_main(
    const short* __restrict__ xbf, const short* __restrict__ Wt,
    const short* __restrict__ Wdec, const short* __restrict__ Dwt,
    const float* __restrict__ bvec, const float* __restrict__ bdec,
    const float* __restrict__ dbv, short* hbuf, unsigned* cnt,
    float* __restrict__ out)
{
  __shared__ short wlds[COLSB*LDSTR];   // 149,504 B
  __shared__ int sSame;
  const int tid = threadIdx.x;
  const int bidx = blockIdx.x;
  const int gb = (bidx & 7)*2 + (bidx >> 7);   // batch group 0..15
  const int gu = (bidx >> 3) & 15;             // unit group 0..15

  unsigned* flags  = cnt + gb*1024;            // 16 flags, 256B spaced
  unsigned* myFlag = flags + gu*64;
  unsigned* regCnt = cnt + 16384 + gb*16;
  unsigned* xcdTab = cnt + 16640 + gb*16;

  // ---- runtime XCD-uniformity check for this group ----
  {
    unsigned xcc;
    asm volatile("s_getreg_b32 %0, hwreg(HW_REG_XCC_ID)" : "=s"(xcc));
    if (tid == 0) {
      __hip_atomic_store(&xcdTab[gu], xcc + 1u, __ATOMIC_RELAXED, __HIP_MEMORY_SCOPE_AGENT);
      __hip_atomic_fetch_add(regCnt, 1u, __ATOMIC_RELEASE, __HIP_MEMORY_SCOPE_AGENT);
      while (__hip_atomic_fetch_add(regCnt, 0u, __ATOMIC_RELAXED, __HIP_MEMORY_SCOPE_AGENT) < 16u)
        __builtin_amdgcn_s_sleep(2);
      __builtin_amdgcn_fence(__ATOMIC_ACQUIRE, "agent");
      unsigned x0 = __hip_atomic_load(&xcdTab[0], __ATOMIC_RELAXED, __HIP_MEMORY_SCOPE_AGENT);
      int same = 1;
      for (int i = 1; i < 16; ++i)
        same &= (__hip_atomic_load(&xcdTab[i], __ATOMIC_RELAXED, __HIP_MEMORY_SCOPE_AGENT) == x0);
      sSame = same;
    }
  }

  // ---- load warm-up weight slice to LDS (col=tid>>3, 72 B each) ----
  {
    const int c = tid >> 3, q = tid & 7;
    const int gate = (c >> 4) & 3;
    const int u = gu*32 + ((c >> 6) << 4) + (c & 15);
    const int gcol = gate*512 + u;
    const short* src = Wt + (size_t)gcol*KTOT + q*72;
    short* dst = wlds + c*LDSTR + q*72;
    #pragma unroll
    for (int j=0;j<9;j++)
      *(bf16x8*)(dst + j*8) = *(const bf16x8*)(src + j*8);
  }
  __syncthreads();
  const bool fastSync = (sSame != 0);

  const int w = tid >> 6, lane = tid & 63;
  const int wm = w >> 1, wn = w & 1;           // 8 row-groups x 2 col-halves
  const int l15 = lane & 15, kh = lane >> 4;

  const int ucol = gu*32 + wn*16 + l15;        // unit column this lane updates
  float bia[4], biaD[4];
  #pragma unroll
  for (int g=0; g<4; ++g){ bia[g] = bvec[g*512 + ucol]; biaD[g] = bdec[g*512 + ucol]; }

  float cst[4] = {};                           // c state (fp32, persistent)
  const int rowA = gb*ROWS + wm*16 + l15;      // A-frag row for this lane
  const short* wbase = wlds + (size_t)(wn*64 + l15)*LDSTR + kh*8;  // g stride 16*LDSTR

  f32x4 acc[4];
  // x-part helper (K 0..63): assigns acc fresh
  auto do_x = [&](int tt) {
    const short* xp = xbf + ((size_t)tt*B_ + rowA)*F_ + kh*8;
    bf16x8 a0 = *(const bf16x8*)(xp);
    bf16x8 a1 = *(const bf16x8*)(xp + 32);
    #pragma unroll
    for (int g=0; g<4; ++g) {
      bf16x8 b0 = *(const bf16x8*)(wbase + (size_t)(16*g)*LDSTR);
      bf16x8 b1 = *(const bf16x8*)(wbase + (size_t)(16*g)*LDSTR + 32);
      f32x4 z = {0.f,0.f,0.f,0.f};
      z = __builtin_amdgcn_mfma_f32_16x16x32_bf16(a0, b0, z, 0,0,0);
      acc[g] = __builtin_amdgcn_mfma_f32_16x16x32_bf16(a1, b1, z, 0,0,0);
    }
  };
  do_x(0);   // h(0)=0 (buf0 zeroed), so step 0 = x-part + zero h-contribution

  for (int t = 0; t < 160; ++t) {
    // ---- wait: all 16 group flags >= t (1 poller lane per flag) ----
    if (t > 0) {
      if (fastSync) {
        if (tid < 64) {
          unsigned* fl = flags + (tid & 15)*64;
          const bool poller = (tid < 16);
          for (;;) {
            unsigned vv = poller
              ? __hip_atomic_load(fl, __ATOMIC_RELAXED, __HIP_MEMORY_SCOPE_AGENT)
              : (unsigned)t;
            if (__ballot(vv >= (unsigned)t) == ~0ull) break;
            __builtin_amdgcn_s_sleep(2);
          }
          asm volatile("buffer_inv sc0" ::: "memory");     // L1 invalidate
          asm volatile("s_waitcnt vmcnt(0)" ::: "memory");
        }
      } else {
        if (tid < 64) {
          unsigned* fl = flags + (tid & 15)*64;
          const bool poller = (tid < 16);
          for (;;) {
            unsigned vv = poller
              ? __hip_atomic_fetch_add(fl, 0u, __ATOMIC_RELAXED, __HIP_MEMORY_SCOPE_AGENT)
              : (unsigned)t;
            if (__ballot(vv >= (unsigned)t) == ~0ull) break;
            __builtin_amdgcn_s_sleep(2);
          }
        }
        if (tid == 0)
          __builtin_amdgcn_fence(__ATOMIC_ACQUIRE, "agent");
      }
      __syncthreads();
    }

    const short* hcur = hbuf + (size_t)(t & 1)*B_*U_;
    short* hnxt = hbuf + (size_t)((t+1) & 1)*B_*U_;

    // ---- pred s = t-128 (reads h(t) just finalized; distributed gu<8, w<4) ----
    if (t >= 128 && gu < 8 && w < 4) {
      const int s = t - 128;
      const int pr0 = gb*ROWS + gu*16 + l15;
      f32x4 pa = {0.f,0.f,0.f,0.f};
      #pragma unroll
      for (int ks=0; ks<16; ++ks) {
        bf16x8 a = *(const bf16x8*)(hcur + (size_t)pr0*U_ + ks*32 + kh*8);
        bf16x8 b = *(const bf16x8*)(Dwt + (size_t)(w*16 + l15)*U_ + ks*32 + kh*8);
        pa = __builtin_amdgcn_mfma_f32_16x16x32_bf16(a, b, pa, 0,0,0);
      }
      const int col = w*16 + l15;
      const float dbc = dbv[col];
      #pragma unroll
      for (int r=0; r<4; ++r) {
        const int orow = gb*ROWS + gu*16 + kh*4 + r;
        out[((size_t)orow*OUTS + s)*F_ + col] = pa[r] + dbc;
      }
    }
    if (t == 159) break;
    if (t == 128) {   // swap k-region 64..575 to folded decode weights
      __syncthreads();
      const int c = tid >> 3, q = tid & 7;
      const int gate = (c >> 4) & 3;
      const int u = gu*32 + ((c >> 6) << 4) + (c & 15);
      const int gcol = gate*512 + u;
      const short* src = Wdec + (size_t)gcol*U_ + q*64;
      short* dst = wlds + c*LDSTR + 64 + q*64;
      #pragma unroll
      for (int j=0;j<8;j++)
        *(bf16x8*)(dst + j*8) = *(const bf16x8*)(src + j*8);
      __syncthreads();
    }

    // ---- h-part: K 64..575, software-pipelined ----
    // 8 A-loads hoisted per half; B double-buffered (prefetch ks+1 under
    // the MFMA cluster of ks).
    {
      const short* hp = hcur + (size_t)rowA*U_ + kh*8;
      bf16x8 A[8];
      bf16x8 Bb[2][4];
      // ---- first half: ks 0..7 ----
      #pragma unroll
      for (int i=0; i<8; ++i) A[i] = *(const bf16x8*)(hp + i*32);
      #pragma unroll
      for (int g=0; g<4; ++g)
        Bb[0][g] = *(const bf16x8*)(wbase + (size_t)(16*g)*LDSTR + 64);
      #pragma unroll
      for (int ks=0; ks<8; ++ks) {
        const int cb = ks & 1, nb = cb ^ 1;
        #pragma unroll
        for (int g=0; g<4; ++g)
          Bb[nb][g] = *(const bf16x8*)(wbase + (size_t)(16*g)*LDSTR + 64 + (ks+1)*32);
        #pragma unroll
        for (int g=0; g<4; ++g)
          acc[g] = __builtin_amdgcn_mfma_f32_16x16x32_bf16(A[ks], Bb[cb][g], acc[g], 0,0,0);
      }
      // ---- second half: ks 8..15 ----
      #pragma unroll
      for (int i=0; i<8; ++i) A[i] = *(const bf16x8*)(hp + (8+i)*32);
      #pragma unroll
      for (int ks=8; ks<16; ++ks) {
        const int cb = ks & 1, nb = cb ^ 1;
        if (ks < 15) {
          #pragma unroll
          for (int g=0; g<4; ++g)
            Bb[nb][g] = *(const bf16x8*)(wbase + (size_t)(16*g)*LDSTR + 64 + (ks+1)*32);
        }
        #pragma unroll
        for (int g=0; g<4; ++g)
          acc[g] = __builtin_amdgcn_mfma_f32_16x16x32_bf16(A[ks-8], Bb[cb][g], acc[g], 0,0,0);
      }
    }

    // ---- gates + state update + h2 store (C/D: col=l15, row=kh*4+r) ----
    {
      const bool warm = (t < T_);
      #pragma unroll
      for (int r=0; r<4; ++r) {
        float zi = acc[0][r] + (warm ? bia[0] : biaD[0]);
        float zf = acc[1][r] + (warm ? bia[1] : biaD[1]);
        float zg = acc[2][r] + (warm ? bia[2] : biaD[2]);
        float zo = acc[3][r] + (warm ? bia[3] : biaD[3]);
        float ig = sigm(zi), fg = sigm(zf), gg = tanh_(zg), og = sigm(zo);
        float c2 = fmaf(fg, cst[r], ig*gg);
        cst[r] = c2;
        float h2 = og*tanh_(c2);
        const int row = gb*ROWS + wm*16 + kh*4 + r;
        hnxt[(size_t)row*U_ + ucol] = f2bf(h2);
      }
    }

    // ---- release: drain stores (syncthreads emits vmcnt(0)), set flag ----
    __syncthreads();
    if (tid == 0) {
      if (fastSync)
        __hip_atomic_store(myFlag, (unsigned)(t+1), __ATOMIC_RELAXED, __HIP_MEMORY_SCOPE_AGENT);
      else
        __hip_atomic_fetch_add(myFlag, 1u, __ATOMIC_RELEASE, __HIP_MEMORY_SCOPE_AGENT);
    }

    // ---- next step's x-part (shadows inter-block flag latency) ----
    #pragma unroll
    for (int g=0; g<4; ++g) acc[g] = (f32x4){0.f,0.f,0.f,0.f};
    if (t + 1 < T_) do_x(t+1);
  }
}

extern "C" void kernel_launch(void* const* d_in, const int* in_sizes, int n_in,
                              void* d_out, int out_size, void* d_ws, size_t ws_size,
                              hipStream_t stream) {
  const float* inputs = (const float*)d_in[0];
  const float* Wx = (const float*)d_in[1];
  const float* Wh = (const float*)d_in[2];
  const float* bv = (const float*)d_in[3];
  const float* Dw = (const float*)d_in[4];
  const float* db = (const float*)d_in[5];
  float* out = (float*)d_out;
  char* ws = (char*)d_ws;
  if (ws_size < WS_TOTAL) return;   // fail loudly (output stays poisoned)

  unsigned* cnt = (unsigned*)(ws + OFF_CNT);
  short* hbuf = (short*)(ws + OFF_HBUF);
  short* Wt   = (short*)(ws + OFF_WT);
  short* Wdec = (short*)(ws + OFF_WDEC);
  short* Dwt  = (short*)(ws + OFF_DWT);
  float* bdec = (float*)(ws + OFF_BDEC);
  short* xbf  = (short*)(ws + OFF_XBF);

  // zero sync area + h buffer 0 (every launch -> deterministic)
  hipMemsetAsync(d_ws, 0, OFF_HBUF + (size_t)B_*U_*2, stream);
  prep_wt  <<<(FOURU*KTOT+255)/256, 256, 0, stream>>>(Wx, Wh, Wt);
  prep_wdec<<<(FOURU*U_ +255)/256, 256, 0, stream>>>(Wh, Wx, Dw, Wdec);
  prep_bdec<<<(FOURU     +255)/256, 256, 0, stream>>>(bv, db, Wx, bdec);
  prep_dwt <<<(F_*U_     +255)/256, 256, 0, stream>>>(Dw, Dwt);
  prep_x   <<<(T_*B_*F_  +255)/256, 256, 0, stream>>>(inputs, xbf);
  lstm_main<<<256, 1024, 0, stream>>>(xbf, Wt, Wdec, Dwt, bv, bdec, db, hbuf, cnt, out);
}